// Round 2
// baseline (856.429 us; speedup 1.0000x reference)
//
#include <hip/hip_runtime.h>
#include <hip/hip_bf16.h>

// ---------------------------------------------------------------------------
// PlanStructuredNetwork — round 4.
//   R3: 787 us. Leaf: 159us, MfmaUtil 28%, VALU 38%, HBM 21%, occ 40% —
//   latency-bound on the 3-barrier per-iteration chain. Bank-conflict 2.5e7
//   matches the INHERENT multi-phase cost of uniform b128/b64 accesses
//   (verified bank-uniform by derivation) — not a fixable conflict.
//   Changes:
//   * skewed pipeline: ONE barrier per phase; phase p = L1(tile p) ||
//     L2(tile p-1) || L3(tile p-2). 3x independent chains per wave,
//     barriers per tile 3 -> 1.
//   * h1/h2 by tile parity; fstage depth-3; cstage depth-2; counted
//     per-phase vmcnt (in-order vmem retirement; never 0 in steady state).
//     nt<6 levels use a predicated vmcnt(0) path (incl. LAST level).
//   * h1/h2: PITCH 128 + 16B-chunk XOR swizzle (chunk ^= row&7, same
//     verified scheme as fstage) -> join LDS 54400B = 3 blocks/CU.
//   * biases in LDS (broadcast reads), freeing ~20 VGPRs for the larger
//     concurrent accumulator set. launch_bounds(256,3).
//   * sched_barrier(0) after each s_barrier pins ds_reads below it.
// ws: 114688 B weights + 128 MB curA + 64 MB curB (~192.1 MB).
// ---------------------------------------------------------------------------

typedef _Float16 f16;
typedef _Float16 f16x8 __attribute__((ext_vector_type(8)));
typedef _Float16 f16x4 __attribute__((ext_vector_type(4)));
typedef float    f32x4 __attribute__((ext_vector_type(4)));

#define MFMA16(a, b, c) __builtin_amdgcn_mfma_f32_16x16x32_f16((a), (b), (c), 0, 0, 0)

#define VMCNT(N) asm volatile("s_waitcnt vmcnt(" #N ")" ::: "memory")
#define LGKM0    asm volatile("s_waitcnt lgkmcnt(0)" ::: "memory")
#define BARRIER() do { __builtin_amdgcn_s_barrier(); __builtin_amdgcn_sched_barrier(0); } while (0)

// ws element offsets (f16) of transposed weights W^T[m][k]
#define OFF_S1 0       // [128][32]
#define OFF_S2 4096    // [128][128]
#define OFF_S3 20480   // [32][128]
#define OFF_J1 24576   // [128][96]
#define OFF_J2 36864   // [128][128]
#define OFF_J3 53248   // [32][128]
#define W_TOTAL 57344
#define CURA_BYTE_OFF 114688   // = W_TOTAL*2

__global__ void prep_weights(const float* __restrict__ sW1,
                             const float* __restrict__ sW2,
                             const float* __restrict__ sW3,
                             const float* __restrict__ jW1,
                             const float* __restrict__ jW2,
                             const float* __restrict__ jW3,
                             f16* __restrict__ wbuf)
{
    int idx = blockIdx.x * 256 + threadIdx.x;
    if (idx >= W_TOTAL) return;
    const float* W;
    int off, M, K;
    if (idx < OFF_S2)      { off = OFF_S1; M = 128; K = 32;  W = sW1; }
    else if (idx < OFF_S3) { off = OFF_S2; M = 128; K = 128; W = sW2; }
    else if (idx < OFF_J1) { off = OFF_S3; M = 32;  K = 128; W = sW3; }
    else if (idx < OFF_J2) { off = OFF_J1; M = 128; K = 96;  W = jW1; }
    else if (idx < OFF_J3) { off = OFF_J2; M = 128; K = 128; W = jW2; }
    else                   { off = OFF_J3; M = 32;  K = 128; W = jW3; }
    int r = idx - off;
    int m = r / K;
    int k = r - m * K;
    wbuf[idx] = (f16)W[(size_t)k * M + m];   // W^T[m][k] = W[k][m]
}

__device__ __forceinline__ void gload16(const void* g, void* l)
{
    // async global->LDS, 16 B/lane; LDS dest = wave-uniform base + lane*16
    __builtin_amdgcn_global_load_lds(
        (const __attribute__((address_space(1))) void*)g,
        (__attribute__((address_space(3))) void*)l,
        16, 0, 0);
}

// Fused 3-layer MLP level, skewed pipeline. Block = 256 threads = 4 waves;
// 32 rows (2 groups of 16) per tile. Wave w owns M-rows [32w,32w+32) of
// layers 1/2; layer 3 (M=32): wave w -> group (w&1), M-half (w>>1).
template <bool LEAF, bool LAST>
__global__ __launch_bounds__(256, 3)
void mlp_level(const float* __restrict__ feats,
               const f16*   __restrict__ cur_in,
               f16*         __restrict__ cur_out,
               float*       __restrict__ out_final,
               const f16*   __restrict__ W1t,
               const f16*   __restrict__ W2t,
               const f16*   __restrict__ W3t,
               const float* __restrict__ b1,
               const float* __restrict__ b2,
               const float* __restrict__ b3,
               int log2n, int foff, int nt)
{
    constexpr int K1  = LEAF ? 32 : 96;
    constexpr int NK1 = LEAF ? 1 : 3;

    // h rows: 128 f16 (256 B), 16B-chunk XOR swizzle by (row&7)
    __shared__ __align__(16) f16   h1[2][32 * 128];
    __shared__ __align__(16) f16   h2[2][32 * 128];
    __shared__ __align__(16) float fstage[3][32 * 32];               // 3 x 4 KB
    __shared__ __align__(16) f16   cstage[(LEAF ? 1 : 2)][32 * 64];  // join: 2 x 4 KB
    __shared__ __align__(16) float bias_lds[288];                    // b1[128] b2[128] b3[32]

    const int tid  = threadIdx.x;
    const int wave = tid >> 6;
    const int lane = tid & 63;
    const int n    = lane & 15;   // node-local index (N dim of MFMA)
    const int q    = lane >> 4;
    const int n7   = n & 7;
    const int mrow = 32 * wave;   // L1/L2 M-slice base
    const int l3g  = wave & 1;    // L3: which group
    const int l3h  = wave >> 1;   // L3: which 16-row M-half

    // staging lane constants: wave w stages rows [8w, 8w+8); LDS dest is
    // linear (gload_lds), source chunk pre-swizzled so LDS slot s of row r
    // holds source chunk s^(r&7).
    const int srow   = (wave << 3) + (lane >> 3);
    const int schunk = (lane & 7) ^ (lane >> 3);

    // ---- biases -> LDS (broadcast-read at use; frees ~20 VGPRs)
    if (tid < 128) bias_lds[tid] = b1[tid];
    else           bias_lds[tid] = b2[tid - 128];
    if (tid < 32)  bias_lds[256 + tid] = b3[tid];

    // ---- resident weights (A[m][k]; m = mrow + 16*mt + n, k = 32*ks+8*q+j)
    f16x8 A1[2][NK1], A2[2][4], A3[4];
#pragma unroll
    for (int mt = 0; mt < 2; ++mt)
#pragma unroll
        for (int ks = 0; ks < NK1; ++ks)
            A1[mt][ks] = *(const f16x8*)(W1t + (size_t)(mrow + 16 * mt + n) * K1 + 32 * ks + 8 * q);
#pragma unroll
    for (int mt = 0; mt < 2; ++mt)
#pragma unroll
        for (int ks = 0; ks < 4; ++ks)
            A2[mt][ks] = *(const f16x8*)(W2t + (size_t)(mrow + 16 * mt + n) * 128 + 32 * ks + 8 * q);
#pragma unroll
    for (int ks = 0; ks < 4; ++ks)
        A3[ks] = *(const f16x8*)(W3t + (size_t)(16 * l3h + n) * 128 + 32 * ks + 8 * q);

    const int stride = gridDim.x * 32;
    const int base   = blockIdx.x * 32;

    // ---- async stage of one 32-row tile
    auto stage_f = [&](int tg0, int sb) {
        int gr = tg0 + srow;
        const float* fsrc;
        if constexpr (LEAF) {
            fsrc = feats + (size_t)gr * 32 + schunk * 4;
        } else {
            int bb = gr >> log2n;
            int ii = gr & ((1 << log2n) - 1);
            fsrc = feats + ((size_t)bb * 1023 + foff + ii) * 32 + schunk * 4;
        }
        gload16(fsrc, &fstage[sb][wave * 256]);
    };
    auto stage_c = [&](int tg0, int sb) {
        int gr = tg0 + srow;
        gload16(cur_in + (size_t)gr * 64 + schunk * 8, &cstage[sb][wave * 512]);
    };

    // ---- layer 1 of tile t: fstage[t%3] (+cstage[t&1]) -> h1[t&1]
    auto doL1 = [&](int t, int g0) {
        const int fb = t % 3;
        const int hb = t & 1;
        f32x4 C[2][2];
#pragma unroll
        for (int mt = 0; mt < 2; ++mt) {
            f32x4 bv = *(const f32x4*)&bias_lds[mrow + 16 * mt + 4 * q];
            C[0][mt] = bv; C[1][mt] = bv;
        }
#pragma unroll
        for (int g = 0; g < 2; ++g) {
            const int r = 16 * g + n;
            f32x4 fa = *(const f32x4*)&fstage[fb][r * 32 + (((2 * q)     ^ n7) << 2)];
            f32x4 fv = *(const f32x4*)&fstage[fb][r * 32 + (((2 * q + 1) ^ n7) << 2)];
            f16x8 Bf;
#pragma unroll
            for (int j = 0; j < 4; ++j) { Bf[j] = (f16)fa[j]; Bf[4 + j] = (f16)fv[j]; }
#pragma unroll
            for (int mt = 0; mt < 2; ++mt) C[g][mt] = MFMA16(A1[mt][0], Bf, C[g][mt]);
            if constexpr (!LEAF) {
                const int cb = t & 1;
                f16x8 cl = *(const f16x8*)&cstage[cb][r * 64 + (( q      ^ n7) << 3)];
                f16x8 cr = *(const f16x8*)&cstage[cb][r * 64 + (((4 + q) ^ n7) << 3)];
#pragma unroll
                for (int mt = 0; mt < 2; ++mt) C[g][mt] = MFMA16(A1[mt][1], cl, C[g][mt]);
#pragma unroll
                for (int mt = 0; mt < 2; ++mt) C[g][mt] = MFMA16(A1[mt][2], cr, C[g][mt]);
            }
        }
        // relu + pack -> h1, swizzled: linear col 32w+16mt+4q -> chunk/rem
#pragma unroll
        for (int g = 0; g < 2; ++g)
#pragma unroll
            for (int mt = 0; mt < 2; ++mt) {
                f16x4 pk;
                pk[0] = (f16)fmaxf(C[g][mt][0], 0.0f);
                pk[1] = (f16)fmaxf(C[g][mt][1], 0.0f);
                pk[2] = (f16)fmaxf(C[g][mt][2], 0.0f);
                pk[3] = (f16)fmaxf(C[g][mt][3], 0.0f);
                const int ch = 4 * wave + 2 * mt + (q >> 1);
                *(f16x4*)&h1[hb][(16 * g + n) * 128 + ((ch ^ n7) << 3) + 4 * (q & 1)] = pk;
            }
    };

    // ---- layer 2 of tile t: h1[t&1] -> h2[t&1]
    auto doL2 = [&](int t) {
        const int hb = t & 1;
        f32x4 C[2][2];
#pragma unroll
        for (int mt = 0; mt < 2; ++mt) {
            f32x4 bv = *(const f32x4*)&bias_lds[128 + mrow + 16 * mt + 4 * q];
            C[0][mt] = bv; C[1][mt] = bv;
        }
#pragma unroll
        for (int ks = 0; ks < 4; ++ks)
#pragma unroll
            for (int g = 0; g < 2; ++g) {
                f16x8 Bf = *(const f16x8*)&h1[hb][(16 * g + n) * 128 + (((4 * ks + q) ^ n7) << 3)];
#pragma unroll
                for (int mt = 0; mt < 2; ++mt) C[g][mt] = MFMA16(A2[mt][ks], Bf, C[g][mt]);
            }
#pragma unroll
        for (int g = 0; g < 2; ++g)
#pragma unroll
            for (int mt = 0; mt < 2; ++mt) {
                f16x4 pk;
                pk[0] = (f16)fmaxf(C[g][mt][0], 0.0f);
                pk[1] = (f16)fmaxf(C[g][mt][1], 0.0f);
                pk[2] = (f16)fmaxf(C[g][mt][2], 0.0f);
                pk[3] = (f16)fmaxf(C[g][mt][3], 0.0f);
                const int ch = 4 * wave + 2 * mt + (q >> 1);
                *(f16x4*)&h2[hb][(16 * g + n) * 128 + ((ch ^ n7) << 3) + 4 * (q & 1)] = pk;
            }
    };

    // ---- layer 3 of tile t: h2[t&1] -> cur_out / out_final
    auto doL3 = [&](int t, int g0) {
        const int hb = t & 1;
        f32x4 C3 = *(const f32x4*)&bias_lds[256 + 16 * l3h + 4 * q];
#pragma unroll
        for (int ks = 0; ks < 4; ++ks) {
            f16x8 Bf = *(const f16x8*)&h2[hb][(16 * l3g + n) * 128 + (((4 * ks + q) ^ n7) << 3)];
            C3 = MFMA16(A3[ks], Bf, C3);
        }
        if constexpr (LAST) {
            if (l3h == 0 && q == 0) out_final[g0 + 16 * l3g + n] = C3[0];
        } else {
            f16x4 pk;
            pk[0] = (f16)C3[0]; pk[1] = (f16)C3[1]; pk[2] = (f16)C3[2]; pk[3] = (f16)C3[3];
            *(f16x4*)(cur_out + (size_t)(g0 + 16 * l3g + n) * 32 + 16 * l3h + 4 * q) = pk;
        }
    };

    // ---- prologue stages: f(0), f(1), c(0)
    stage_f(base, 0);
    if (nt > 1) stage_f(base + stride, 1);
    if constexpr (!LEAF) stage_c(base, 0);
    LGKM0;   // bias_lds writes drained before first barrier

    if (nt >= 6) {
        // Counted-vmcnt path. Per-wave vmem issue order per full phase x:
        //   [VM; BAR; c(x+1); f(x+2); compute; store(x-2); LGKM]
        // vmcnt retires in issue order -> constants derived per phase.
        // p=0: leaf needs f(0), newer={f(1)} -> VM(1); join needs c(0), newer={} -> VM(0)
        if constexpr (LEAF) { VMCNT(1); } else { VMCNT(0); }
        BARRIER();
        if constexpr (!LEAF) stage_c(base + stride, 1);
        stage_f(base + 2 * stride, 2);
        doL1(0, base);
        LGKM0;
        // p=1: need f(1)/c(1); newer = {f(2)} -> VM(1)
        VMCNT(1); BARRIER();
        if constexpr (!LEAF) stage_c(base + 2 * stride, 0);
        stage_f(base + 3 * stride, 0);
        doL1(1, base + stride); doL2(0);
        LGKM0;
        // p=2: need f(2)/c(2); newer = {f(3)} -> VM(1)
        VMCNT(1); BARRIER();
        if constexpr (!LEAF) stage_c(base + 3 * stride, 1);
        stage_f(base + 4 * stride, 1);
        doL1(2, base + 2 * stride); doL2(1); doL3(0, base);
        LGKM0;
        // p=3: need f(3)/c(3); newer = {f(4), store(0)} -> VM(2)
        VMCNT(2); BARRIER();
        if constexpr (!LEAF) stage_c(base + 4 * stride, 0);
        stage_f(base + 5 * stride, 2);
        doL1(3, base + 3 * stride); doL2(2); doL3(1, base + stride);
        LGKM0;
        // steady p = 4 .. nt-2:
        //   leaf: need f(p), newer = {store(p-4), f(p+1), store(p-3)} -> VM(3)
        //   join: need c(p), newer = {f(p+1), store(p-3)}             -> VM(2)
        for (int p = 4; p <= nt - 2; ++p) {
            if constexpr (LEAF) { VMCNT(3); } else { VMCNT(2); }
            BARRIER();
            if constexpr (!LEAF) stage_c(base + (p + 1) * stride, (p + 1) & 1);
            if (p + 2 < nt) stage_f(base + (p + 2) * stride, (p + 2) % 3);
            doL1(p, base + p * stride);
            doL2(p - 1);
            doL3(p - 2, base + (p - 2) * stride);
            LGKM0;
        }
        // p = nt-1: leaf need f(nt-1), newer={store(nt-5),store(nt-4)} -> VM(2)
        //           join need c(nt-1), newer={store(nt-4)}             -> VM(1)
        if constexpr (LEAF) { VMCNT(2); } else { VMCNT(1); }
        BARRIER();
        doL1(nt - 1, base + (nt - 1) * stride);
        doL2(nt - 2);
        doL3(nt - 3, base + (nt - 3) * stride);
        LGKM0;
        // p = nt: no staged reads -> no VM needed
        BARRIER();
        doL2(nt - 1);
        doL3(nt - 2, base + (nt - 2) * stride);
        LGKM0;
        // p = nt+1
        BARRIER();
        doL3(nt - 1, base + (nt - 1) * stride);
    } else {
        // generic predicated path (nt in {1,2,4}; incl. LAST level)
        for (int p = 0; p <= nt + 1; ++p) {
            VMCNT(0); BARRIER();
            if constexpr (!LEAF) { if (p + 1 < nt) stage_c(base + (p + 1) * stride, (p + 1) & 1); }
            if (p + 2 < nt) stage_f(base + (p + 2) * stride, (p + 2) % 3);
            if (p < nt)              doL1(p, base + p * stride);
            if (p >= 1 && p <= nt)   doL2(p - 1);
            if (p >= 2)              doL3(p - 2, base + (p - 2) * stride);
            LGKM0;
        }
    }
}

extern "C" void kernel_launch(void* const* d_in, const int* in_sizes, int n_in,
                              void* d_out, int out_size, void* d_ws, size_t ws_size,
                              hipStream_t stream)
{
    const float* leaf_feats     = (const float*)d_in[0];
    const float* internal_feats = (const float*)d_in[1];
    const float* sW1 = (const float*)d_in[2];  const float* sb1 = (const float*)d_in[3];
    const float* sW2 = (const float*)d_in[4];  const float* sb2 = (const float*)d_in[5];
    const float* sW3 = (const float*)d_in[6];  const float* sb3 = (const float*)d_in[7];
    const float* jW1 = (const float*)d_in[8];  const float* jb1 = (const float*)d_in[9];
    const float* jW2 = (const float*)d_in[10]; const float* jb2 = (const float*)d_in[11];
    const float* jW3 = (const float*)d_in[12]; const float* jb3 = (const float*)d_in[13];

    f16* wbuf = (f16*)d_ws;
    f16* curA = (f16*)((char*)d_ws + CURA_BYTE_OFF);                 // 128 MB
    f16* curB = (f16*)((char*)d_ws + CURA_BYTE_OFF + 134217728);     // 64 MB

    prep_weights<<<(W_TOTAL + 255) / 256, 256, 0, stream>>>(
        sW1, sW2, sW3, jW1, jW2, jW3, wbuf);

    // leaf level: 2048*1024 rows, 65536 tiles of 32 rows; nt = 32
    mlp_level<true, false><<<2048, 256, 0, stream>>>(
        leaf_feats, nullptr, curA, nullptr,
        wbuf + OFF_S1, wbuf + OFF_S2, wbuf + OFF_S3,
        sb1, sb2, sb3,
        0, 0, 32);

    // join levels
    const f16* cin = curA;
    f16* cout = curB;
    int off = 0, lg = 9;
    for (int nlev = 512; nlev >= 1; nlev >>= 1, --lg) {
        int rows  = 2048 * nlev;
        int iters = rows / 32;
        int grid  = iters < 2048 ? iters : 2048;
        int nt    = iters / grid;
        if (nlev == 1) {
            mlp_level<false, true><<<grid, 256, 0, stream>>>(
                internal_feats, cin, cout, (float*)d_out,
                wbuf + OFF_J1, wbuf + OFF_J2, wbuf + OFF_J3,
                jb1, jb2, jb3,
                lg, off, nt);
        } else {
            mlp_level<false, false><<<grid, 256, 0, stream>>>(
                internal_feats, cin, cout, (float*)d_out,
                wbuf + OFF_J1, wbuf + OFF_J2, wbuf + OFF_J3,
                jb1, jb2, jb3,
                lg, off, nt);
        }
        off += nlev;
        f16* t = cout; cout = (f16*)cin; cin = t;
    }
}